// Round 1
// baseline (78.708 us; speedup 1.0000x reference)
//
#include <hip/hip_runtime.h>

// Problem: x (16384 x 4096 fp32), W (4096 x 4096 fp32)
// out[b] = 0.75 * sum_k x[b,k] * colsum(W)[k], shape (16384, 1) fp32.
// Pure memory-bound: 320 MB compulsory read -> ~51 us roofline @ 6.3 TB/s.

#define N_COLS 4096
#define W_ROWS 4096
#define BATCH  16384
#define SCALE  0.75f   // SCALING_FACTOR / 2.0 = 1.5/2

// ---------------- Kernel 1: column-sum of W into ws[0..4095] ----------------
// grid = (4 column tiles, 128 row chunks); block = 256 threads.
// Each thread owns 4 consecutive columns (float4), accumulates 32 rows,
// then one atomicAdd per column (128 contenders/address total).
__global__ __launch_bounds__(256) void colsum_kernel(const float* __restrict__ W,
                                                     float* __restrict__ ws) {
    const int colBase = blockIdx.x * 1024 + threadIdx.x * 4;
    const int row0    = blockIdx.y * 32;
    float4 acc = make_float4(0.f, 0.f, 0.f, 0.f);
#pragma unroll 8
    for (int r = 0; r < 32; ++r) {
        const float4 v = *reinterpret_cast<const float4*>(
            &W[(size_t)(row0 + r) * N_COLS + colBase]);
        acc.x += v.x; acc.y += v.y; acc.z += v.z; acc.w += v.w;
    }
    atomicAdd(&ws[colBase + 0], acc.x);
    atomicAdd(&ws[colBase + 1], acc.y);
    atomicAdd(&ws[colBase + 2], acc.z);
    atomicAdd(&ws[colBase + 3], acc.w);
}

// ---------------- Kernel 2: out[b] = SCALE * dot(x[b,:], ws) ----------------
// One wave (64 lanes) per row; 4 waves per block; grid = 16384/4 = 4096.
// Lane l reads float4s at stride 64*16B -> coalesced 1KB per wave per instr.
// ws (16 KB) stays L1/L2 resident.
__global__ __launch_bounds__(256) void rowdot_kernel(const float* __restrict__ x,
                                                     const float* __restrict__ ws,
                                                     float* __restrict__ out) {
    const int wave = threadIdx.x >> 6;
    const int lane = threadIdx.x & 63;
    const int row  = blockIdx.x * 4 + wave;
    const float* __restrict__ xr = x + (size_t)row * N_COLS;

    float acc = 0.f;
#pragma unroll
    for (int i = 0; i < 16; ++i) {
        const int idx = (i * 64 + lane) * 4;
        const float4 a = *reinterpret_cast<const float4*>(&xr[idx]);
        const float4 b = *reinterpret_cast<const float4*>(&ws[idx]);
        acc += a.x * b.x + a.y * b.y + a.z * b.z + a.w * b.w;
    }
#pragma unroll
    for (int off = 32; off >= 1; off >>= 1)
        acc += __shfl_down(acc, off, 64);

    if (lane == 0) out[row] = acc * SCALE;
}

extern "C" void kernel_launch(void* const* d_in, const int* in_sizes, int n_in,
                              void* d_out, int out_size, void* d_ws, size_t ws_size,
                              hipStream_t stream) {
    const float* x = (const float*)d_in[0];   // (16384, 4096)
    const float* W = (const float*)d_in[1];   // (4096, 4096)
    float* out = (float*)d_out;               // (16384, 1)
    float* ws  = (float*)d_ws;                // >= 16 KB scratch

    // Workspace is poisoned 0xAA by the harness; zero the colsum vector.
    hipMemsetAsync(ws, 0, N_COLS * sizeof(float), stream);

    colsum_kernel<<<dim3(4, 128), 256, 0, stream>>>(W, ws);
    rowdot_kernel<<<BATCH / 4, 256, 0, stream>>>(x, ws, out);
}

// Round 3
// 75.606 us; speedup vs baseline: 1.0410x; 1.0410x over previous
//
#include <hip/hip_runtime.h>

// x (16384 x 4096 fp32), W (4096 x 4096 fp32)
// out[b] = 0.75 * dot(x[b,:], colsum(W)), shape (16384,1) fp32.
// Memory-bound: 320 MB compulsory read -> ~47-51 us roofline.

#define N_COLS 4096
#define BATCH  16384
#define SCALE  0.75f   // SCALING_FACTOR / 2.0

typedef float f32x4 __attribute__((ext_vector_type(4)));

__device__ __forceinline__ f32x4 ntload4(const float* p) {
    return __builtin_nontemporal_load(reinterpret_cast<const f32x4*>(p));
}

// ---------------- Kernel 1: column-sum of W into ws[0..4095] ----------------
// grid = (4 col-tiles, 64 row-chunks) = 256 blocks (1/CU); block = 256.
// Thread owns 4 consecutive cols (f32x4), accumulates 64 rows in regs,
// then one atomicAdd per col (64 contenders/address).
__global__ __launch_bounds__(256) void colsum_kernel(const float* __restrict__ W,
                                                     float* __restrict__ ws) {
    const int colBase = blockIdx.x * 1024 + threadIdx.x * 4;
    const int row0    = blockIdx.y * 64;
    f32x4 acc = {0.f, 0.f, 0.f, 0.f};
#pragma unroll 8
    for (int r = 0; r < 64; ++r) {
        acc += ntload4(&W[(size_t)(row0 + r) * N_COLS + colBase]);
    }
    atomicAdd(&ws[colBase + 0], acc.x);
    atomicAdd(&ws[colBase + 1], acc.y);
    atomicAdd(&ws[colBase + 2], acc.z);
    atomicAdd(&ws[colBase + 3], acc.w);
}

// ---------------- Kernel 2: out[b] = SCALE * dot(x[b,:], ws) ----------------
// 4 rows per wave, 4 waves per 256-thread block -> 16 rows/block,
// grid = 16384/16 = 1024 blocks. Per iteration: 1 cached ws f32x4 +
// 4 nontemporal x f32x4 loads, 16 FMAs. Lane 0 stores 4 outputs as float4.
__global__ __launch_bounds__(256) void rowdot_kernel(const float* __restrict__ x,
                                                     const float* __restrict__ ws,
                                                     float* __restrict__ out) {
    const int wave = threadIdx.x >> 6;
    const int lane = threadIdx.x & 63;
    const int row0 = (blockIdx.x * 4 + wave) * 4;   // 4 consecutive rows

    const float* __restrict__ x0 = x + (size_t)(row0 + 0) * N_COLS;
    const float* __restrict__ x1 = x + (size_t)(row0 + 1) * N_COLS;
    const float* __restrict__ x2 = x + (size_t)(row0 + 2) * N_COLS;
    const float* __restrict__ x3 = x + (size_t)(row0 + 3) * N_COLS;

    float a0 = 0.f, a1 = 0.f, a2 = 0.f, a3 = 0.f;
#pragma unroll
    for (int i = 0; i < 16; ++i) {
        const int idx = (i * 64 + lane) * 4;
        const f32x4 c  = *reinterpret_cast<const f32x4*>(&ws[idx]); // cached
        const f32x4 v0 = ntload4(&x0[idx]);
        const f32x4 v1 = ntload4(&x1[idx]);
        const f32x4 v2 = ntload4(&x2[idx]);
        const f32x4 v3 = ntload4(&x3[idx]);
        a0 += v0.x * c.x + v0.y * c.y + v0.z * c.z + v0.w * c.w;
        a1 += v1.x * c.x + v1.y * c.y + v1.z * c.z + v1.w * c.w;
        a2 += v2.x * c.x + v2.y * c.y + v2.z * c.z + v2.w * c.w;
        a3 += v3.x * c.x + v3.y * c.y + v3.z * c.z + v3.w * c.w;
    }
#pragma unroll
    for (int off = 32; off >= 1; off >>= 1) {
        a0 += __shfl_down(a0, off, 64);
        a1 += __shfl_down(a1, off, 64);
        a2 += __shfl_down(a2, off, 64);
        a3 += __shfl_down(a3, off, 64);
    }
    if (lane == 0) {
        f32x4 r = {a0 * SCALE, a1 * SCALE, a2 * SCALE, a3 * SCALE};
        *reinterpret_cast<f32x4*>(&out[row0]) = r;
    }
}

extern "C" void kernel_launch(void* const* d_in, const int* in_sizes, int n_in,
                              void* d_out, int out_size, void* d_ws, size_t ws_size,
                              hipStream_t stream) {
    const float* x = (const float*)d_in[0];   // (16384, 4096)
    const float* W = (const float*)d_in[1];   // (4096, 4096)
    float* out = (float*)d_out;               // (16384, 1)
    float* ws  = (float*)d_ws;

    (void)hipMemsetAsync(ws, 0, N_COLS * sizeof(float), stream);
    colsum_kernel<<<dim3(4, 64), 256, 0, stream>>>(W, ws);
    rowdot_kernel<<<BATCH / 16, 256, 0, stream>>>(x, ws, out);
}